// Round 6
// baseline (29059.296 us; speedup 1.0000x reference)
//
#include <hip/hip_runtime.h>
#include <hip/hip_cooperative_groups.h>

namespace cg = cooperative_groups;

// R16: R15 skeleton + shuffle-tree reduce + per-wave release + x prefetch.
// 256 WGs x 512 thr (1/CU). WG = (dir, batch-group of 8, 16-cell slice).
// 8 independent (dir,bg) pipelines of 32 WGs. Per step critical chain:
//   x-GEMM (overlaps peers' tail) -> poll 64 packed slots -> h-stage (LLC)
//   -> h-GEMM (reg Whh) -> 5-stage shuffle reduce -> gates -> pointwise
//   (waves 6-7) -> coalesced sc1 publish -> per-wave RELEASE flags.
// 3 syncthreads/step. No LDS partial dump. No RMW atomics, no cache-wide
// fences; weights L2-resident; Whh slice in registers.

#define Bv 32
#define Tv 512
#define Dv 512
#define Hv 512
#define XS 520            // x LDS row stride (floats)
#define HS 520            // h LDS row stride

__device__ __forceinline__ float sigmf_(float x) { return 1.0f / (1.0f + __expf(-x)); }
__device__ __forceinline__ float tanhf_(float x) { return 2.0f / (1.0f + __expf(-2.0f * x)) - 1.0f; }

__global__ __launch_bounds__(512, 2) void bilstm_coop6(
    const float* __restrict__ x, const int* __restrict__ lengths,
    const float* __restrict__ Wih_f, const float* __restrict__ Whh_f,
    const float* __restrict__ bih_f, const float* __restrict__ bhh_f,
    const float* __restrict__ Wih_b, const float* __restrict__ Whh_b,
    const float* __restrict__ bih_b, const float* __restrict__ bhh_b,
    float* __restrict__ out, unsigned int* __restrict__ cnt)  // cnt: 8 groups x 64 uints
{
    __shared__ float xb[2][8 * XS];    // double-buffered x stage (33 KB)
    __shared__ float hu[8 * HS];       // h stage (16.6 KB)
    __shared__ float gates[64 * 9];    // [row 64][b 8] pad 9
    __shared__ float bias_s[64];

    const int tid  = threadIdx.x;
    const int w    = blockIdx.x;

    // blockIdx -> XCD is (w & 7). XCDs 0..3 = dir 0, XCDs 4..7 = dir 1.
    // cslice is XCD-local (8 per XCD) -> per-XCD Wih slice = 1MB, L2-resident.
    const int xcd    = w & 7;
    const int slot   = w >> 3;                      // 0..31
    const int dir    = xcd >> 2;
    const int cslice = (xcd & 3) * 8 + (slot & 7);  // 0..31
    const int bg     = slot >> 3;                   // 0..3
    const int c0     = cslice * 16;                 // first of 16 cells
    const int b0     = bg * 8;                      // first of 8 batches
    const int group  = dir * 4 + bg;                // 0..7

    unsigned int* slotA = cnt + (size_t)group * 64 + cslice;        // wave-6 flag
    unsigned int* slotB = cnt + (size_t)group * 64 + 32 + cslice;   // wave-7 flag

    const float* Wih = dir ? Wih_b : Wih_f;
    const float* Whh = dir ? Whh_b : Whh_f;
    const float* bih = dir ? bih_b : bih_f;
    const float* bhh = dir ? bhh_b : bhh_f;

    // ---- prologue ----
    if (tid == 0) {
        __hip_atomic_store(slotA, 0u, __ATOMIC_RELAXED, __HIP_MEMORY_SCOPE_AGENT);
        __hip_atomic_store(slotB, 0u, __ATOMIC_RELAXED, __HIP_MEMORY_SCOPE_AGENT);
    }
    if (tid < 64) {
        int g = tid >> 4, cell = tid & 15;
        int rg = g * Hv + c0 + cell;
        bias_s[tid] = bih[rg] + bhh[rg];
    }
    // stage x(0) into xb[0]
    {
        const int t0 = dir ? (Tv - 1) : 0;
        #pragma unroll
        for (int j = 0; j < 2; ++j) {
            int F  = tid + j * 512;
            int bl = F >> 7, cf = F & 127;
            *(float4*)(&xb[0][bl * XS + cf * 4]) =
                *(const float4*)(x + ((size_t)(b0 + bl) * Tv + t0) * Dv + cf * 4);
        }
    }
    cg::this_grid().sync();   // once per launch: slots zeroed + xb[0] ready

    // thread tile: pos = 4 gate-rows, all 8 batches, 32-float k-segment
    const int pos  = tid >> 5;      // 0..15 -> rows pos*4 .. pos*4+3 (of 64)
    const int kseg = tid & 31;      // 0..31 (== lane within half-wave)

    int wrow[4];
    #pragma unroll
    for (int i = 0; i < 4; ++i) {
        int r = pos * 4 + i;
        wrow[i] = (r >> 4) * Hv + c0 + (r & 15);
    }

    // step-invariant Whh slice in registers (16 x float4)
    float4 whr[4][4];
    #pragma unroll
    for (int j = 0; j < 4; ++j)
        #pragma unroll
        for (int i = 0; i < 4; ++i)
            whr[j][i] = *(const float4*)(Whh + (size_t)wrow[i] * Dv
                                             + (j * 32 + kseg) * 4);

    // tail threads (waves 6,7): idx 0..127 -> (batch, cell)
    const int tidx    = tid - 384;          // valid when tid >= 384
    const int pw_ib   = tidx >> 4;          // 0..7
    const int pw_cell = tidx & 15;          // 0..15
    float cst_r = 0.0f;
    int   len_r = 0;
    if (tid >= 384) len_r = lengths[b0 + pw_ib];

    // shuffle-reduce final index: bit-reversal of lane (5 bits)
    const int Lr = ((kseg & 1) << 4) | ((kseg & 2) << 2) | (kseg & 4)
                 | ((kseg & 8) >> 2) | ((kseg & 16) >> 4);
    const int g_row = pos * 4 + (Lr >> 3);     // gate row this thread will write
    const int g_ib  = Lr & 7;                  // batch it will write

    for (int s = 0; s < Tv; ++s) {
        const int t   = dir ? (Tv - 1 - s) : s;
        const int cur = s & 1;

        // ---- 1. x-part GEMM from xb[cur] ----
        float acc[4][8];
        #pragma unroll
        for (int i = 0; i < 4; ++i)
            #pragma unroll
            for (int ib = 0; ib < 8; ++ib) acc[i][ib] = 0.0f;

        #pragma unroll
        for (int j = 0; j < 4; ++j) {
            const int col = (j * 32 + kseg) * 4;
            float4 wv[4];
            #pragma unroll
            for (int i = 0; i < 4; ++i)
                wv[i] = *(const float4*)(Wih + (size_t)wrow[i] * Dv + col);
            float4 xv[8];
            #pragma unroll
            for (int ib = 0; ib < 8; ++ib)
                xv[ib] = *(const float4*)(&xb[cur][ib * XS + col]);
            #pragma unroll
            for (int i = 0; i < 4; ++i)
                #pragma unroll
                for (int ib = 0; ib < 8; ++ib)
                    acc[i][ib] += wv[i].x * xv[ib].x + wv[i].y * xv[ib].y
                                + wv[i].z * xv[ib].z + wv[i].w * xv[ib].w;
        }

        // ---- 2. prefetch x(s+1) into xb[cur^1] (off critical path) ----
        if (s + 1 < Tv) {
            const int tn = dir ? (Tv - 2 - s) : (s + 1);
            #pragma unroll
            for (int j = 0; j < 2; ++j) {
                int F  = tid + j * 512;
                int bl = F >> 7, cf = F & 127;
                *(float4*)(&xb[cur ^ 1][bl * XS + cf * 4]) =
                    *(const float4*)(x + ((size_t)(b0 + bl) * Tv + tn) * Dv + cf * 4);
            }
        }

        // ---- 3. WAIT: wave 2 polls 64 packed slots (4 lines) ----
        if (s > 0 && tid >= 128 && tid < 192) {
            const unsigned int tgt = (unsigned int)s;
            const unsigned int* sl = cnt + (size_t)group * 64 + (tid - 128);
            while (__hip_atomic_load(sl, __ATOMIC_RELAXED,
                                     __HIP_MEMORY_SCOPE_AGENT) < tgt)
                __builtin_amdgcn_s_sleep(1);
        }
        __syncthreads();   // [B] barrier passed; xb[cur^1] also complete

        // ---- 4. stage h_{s-1} from out (fresh addresses -> L2 miss -> LLC) ----
        if (s == 0) {
            #pragma unroll
            for (int j = 0; j < 2; ++j) {
                int F  = tid + j * 512;
                int bl = F >> 7, cf = F & 127;
                *(float4*)(hu + bl * HS + cf * 4) = make_float4(0.f, 0.f, 0.f, 0.f);
            }
        } else {
            const int tp = dir ? (t + 1) : (t - 1);
            #pragma unroll
            for (int j = 0; j < 2; ++j) {
                int F  = tid + j * 512;
                int bl = F >> 7, cf = F & 127;
                *(float4*)(hu + bl * HS + cf * 4) =
                    *(const float4*)(out + ((size_t)(b0 + bl) * Tv + tp) * (2 * Hv)
                                         + dir * Hv + cf * 4);
            }
        }
        __syncthreads();   // [C] hu ready

        // ---- 5. h-part GEMM: pure LDS + register weights ----
        #pragma unroll
        for (int j = 0; j < 4; ++j) {
            const int col = (j * 32 + kseg) * 4;
            float4 hv[8];
            #pragma unroll
            for (int ib = 0; ib < 8; ++ib)
                hv[ib] = *(const float4*)(hu + ib * HS + col);
            #pragma unroll
            for (int i = 0; i < 4; ++i)
                #pragma unroll
                for (int ib = 0; ib < 8; ++ib)
                    acc[i][ib] += whr[j][i].x * hv[ib].x + whr[j][i].y * hv[ib].y
                                + whr[j][i].z * hv[ib].z + whr[j][i].w * hv[ib].w;
        }

        // ---- 6. 5-stage shuffle-tree reduce over the 32 ksegs ----
        // lanes 0..31 / 32..63 of each wave hold kseg 0..31 for one pos each;
        // partners lane^d stay within the half. Final: lane holds the full
        // sum for value index rev5(lane) -> (row, batch) = (g_row, g_ib).
        {
            float v[32];
            #pragma unroll
            for (int i = 0; i < 4; ++i)
                #pragma unroll
                for (int ib = 0; ib < 8; ++ib) v[i * 8 + ib] = acc[i][ib];

            #pragma unroll
            for (int st = 0; st < 5; ++st) {
                const int d    = 1 << st;
                const int half = 16 >> st;
                const bool up  = (kseg & d) != 0;
                #pragma unroll
                for (int k = 0; k < 16; ++k) {
                    if (k < half) {
                        float keep = up ? v[k + half] : v[k];
                        float send = up ? v[k]        : v[k + half];
                        float recv = __shfl_xor(send, d, 64);
                        v[k] = keep + recv;
                    }
                }
            }
            gates[g_row * 9 + g_ib] = v[0] + bias_s[g_row];
        }
        __syncthreads();   // [F] gates ready; waves 0..5 sprint to next x-GEMM

        // ---- 7. TAIL (waves 6,7): pointwise, coalesced sc1 publish ----
        if (tid >= 384) {
            float gi = sigmf_(gates[( 0 + pw_cell) * 9 + pw_ib]);
            float gf = sigmf_(gates[(16 + pw_cell) * 9 + pw_ib]);
            float gg = tanhf_(gates[(32 + pw_cell) * 9 + pw_ib]);
            float go = sigmf_(gates[(48 + pw_cell) * 9 + pw_ib]);
            float cn = gf * cst_r + gi * gg;
            float hn = go * tanhf_(cn);
            const bool vld = (t < len_r);
            float hpv = hu[pw_ib * HS + c0 + pw_cell];   // previous h (hold)
            float ho = vld ? hn : hpv;
            cst_r = vld ? cn : cst_r;
            __hip_atomic_store(out + ((size_t)(b0 + pw_ib) * Tv + t) * (2 * Hv)
                                   + dir * Hv + c0 + pw_cell,
                               ho, __ATOMIC_RELAXED, __HIP_MEMORY_SCOPE_AGENT);
        }
        // ---- 8. per-wave RELEASE (waits only that wave's stores) ----
        if (tid == 384)
            __hip_atomic_store(slotA, (unsigned int)(s + 1),
                               __ATOMIC_RELEASE, __HIP_MEMORY_SCOPE_AGENT);
        if (tid == 448)
            __hip_atomic_store(slotB, (unsigned int)(s + 1),
                               __ATOMIC_RELEASE, __HIP_MEMORY_SCOPE_AGENT);
        // no trailing sync: next step's [B] rejoins everyone, and hu isn't
        // overwritten until after the next [B] (tail's hpv read is safe).
    }
}

// ---------------- fallback: R10 kernel (unchanged, correct, slow) ----------------
__global__ __launch_bounds__(1024, 1) void bilstm_simple(
    const float* __restrict__ x,
    const int* __restrict__ lengths,
    const float* __restrict__ Wih_f, const float* __restrict__ Whh_f,
    const float* __restrict__ bih_f, const float* __restrict__ bhh_f,
    const float* __restrict__ Wih_b, const float* __restrict__ Whh_b,
    const float* __restrict__ bih_b, const float* __restrict__ bhh_b,
    float* __restrict__ out)
{
    __shared__ float xh[Dv + Hv];
    __shared__ float cst[Hv];
    __shared__ float gates[4 * Hv];
    __shared__ float bias[4 * Hv];

    const int tid  = threadIdx.x;
    const int wave = tid >> 6;
    const int lane = tid & 63;
    const int dir  = blockIdx.x >> 5;
    const int b    = blockIdx.x & 31;

    const float* Wih = dir ? Wih_b : Wih_f;
    const float* Whh = dir ? Whh_b : Whh_f;
    const float* bih = dir ? bih_b : bih_f;
    const float* bhh = dir ? bhh_b : bhh_f;

    for (int i = tid; i < 4 * Hv; i += 1024) bias[i] = bih[i] + bhh[i];
    for (int i = tid; i < Hv; i += 1024) { xh[Dv + i] = 0.f; cst[i] = 0.f; }
    const int len = lengths[b];

    const float* Wbase = (lane < 32) ? Wih : Whh;
    const int koff = (lane & 31) * 16;

    for (int s = 0; s < Tv; ++s) {
        const int t = dir ? (Tv - 1 - s) : s;
        __syncthreads();
        for (int i = tid; i < Dv; i += 1024)
            xh[i] = x[((size_t)b * Tv + t) * Dv + i];
        __syncthreads();

        float4 xr0 = *(const float4*)(xh + lane * 16 + 0);
        float4 xr1 = *(const float4*)(xh + lane * 16 + 4);
        float4 xr2 = *(const float4*)(xh + lane * 16 + 8);
        float4 xr3 = *(const float4*)(xh + lane * 16 + 12);

        #pragma unroll 4
        for (int rr = 0; rr < 128; ++rr) {
            const int row = wave * 128 + rr;
            const float4* wr = (const float4*)(Wbase + (size_t)row * 512 + koff);
            const float4 w0 = wr[0], w1 = wr[1], w2 = wr[2], w3 = wr[3];
            float acc = w0.x * xr0.x + w0.y * xr0.y + w0.z * xr0.z + w0.w * xr0.w
                      + w1.x * xr1.x + w1.y * xr1.y + w1.z * xr1.z + w1.w * xr1.w
                      + w2.x * xr2.x + w2.y * xr2.y + w2.z * xr2.z + w2.w * xr2.w
                      + w3.x * xr3.x + w3.y * xr3.y + w3.z * xr3.z + w3.w * xr3.w;
            #pragma unroll
            for (int off = 32; off > 0; off >>= 1)
                acc += __shfl_xor(acc, off, 64);
            if (lane == 0) gates[row] = acc;
        }
        __syncthreads();

        if (tid < Hv) {
            const int cc = tid;
            const float gi = sigmf_(gates[0 * Hv + cc] + bias[0 * Hv + cc]);
            const float gf = sigmf_(gates[1 * Hv + cc] + bias[1 * Hv + cc]);
            const float gg = tanhf_(gates[2 * Hv + cc] + bias[2 * Hv + cc]);
            const float go = sigmf_(gates[3 * Hv + cc] + bias[3 * Hv + cc]);
            const float cn = gf * cst[cc] + gi * gg;
            const float hn = go * tanhf_(cn);
            const bool v = (t < len);
            const float hnew = v ? hn : xh[Dv + cc];
            cst[cc] = v ? cn : cst[cc];
            xh[Dv + cc] = hnew;
            out[((size_t)b * Tv + t) * (2 * Hv) + dir * Hv + cc] = hnew;
        }
    }
}

extern "C" void kernel_launch(void* const* d_in, const int* in_sizes, int n_in,
                              void* d_out, int out_size, void* d_ws, size_t ws_size,
                              hipStream_t stream) {
    (void)out_size;

    const void *xv, *len_p, *Wihf, *Whhf, *bihf, *bhhf, *Wihb, *Whhb, *bihb, *bhhb;
    if (n_in == 10 && in_sizes[9] == 8388608 && in_sizes[8] == 32) {
        // alphabetical pytree order fallback
        Whhb = d_in[0]; Whhf = d_in[1]; Wihb = d_in[2]; Wihf = d_in[3];
        bhhb = d_in[4]; bhhf = d_in[5]; bihb = d_in[6]; bihf = d_in[7];
        len_p = d_in[8]; xv = d_in[9];
    } else {
        // documented dict order
        xv = d_in[0]; len_p = d_in[1];
        Wihf = d_in[2]; Whhf = d_in[3]; bihf = d_in[4]; bhhf = d_in[5];
        Wihb = d_in[6]; Whhb = d_in[7]; bihb = d_in[8]; bhhb = d_in[9];
    }

    const float* xf  = (const float*)xv;
    const int*   lp  = (const int*)len_p;
    const float* wif = (const float*)Wihf;  const float* whf = (const float*)Whhf;
    const float* bif = (const float*)bihf;  const float* bhf = (const float*)bhhf;
    const float* wib = (const float*)Wihb;  const float* whb = (const float*)Whhb;
    const float* bib = (const float*)bihb;  const float* bhb = (const float*)bhhb;
    float* outp = (float*)d_out;
    unsigned int* cntp = (unsigned int*)d_ws;

    if (ws_size >= 8 * 64 * sizeof(unsigned int)) {   // 2 KB of slots
        void* args[12] = { &xf, &lp, &wif, &whf, &bif, &bhf,
                           &wib, &whb, &bib, &bhb, &outp, &cntp };
        hipError_t e = hipLaunchCooperativeKernel((const void*)bilstm_coop6,
                                                  dim3(256), dim3(512),
                                                  args, 0, stream);
        if (e == hipSuccess) return;
    }

    // fallback: R10 kernel
    bilstm_simple<<<dim3(64), dim3(1024), 0, stream>>>(
        xf, lp, wif, whf, bif, bhf, wib, whb, bib, bhb, outp);
}

// Round 7
// 9020.953 us; speedup vs baseline: 3.2213x; 3.2213x over previous
//
#include <hip/hip_runtime.h>
#include <hip/hip_cooperative_groups.h>

namespace cg = cooperative_groups;

// R17: R15 structure (proven 5.3ms, register-safe) + two register-neutral
// grafts from R16: (1) x double-buffer prefetch (kills x-stage sync),
// (2) tail on waves 6-7 with per-wave RELEASE flags (kills full-WG drain
// sync). LDS partial-dump reduce kept from R15 (NO shuffle-tree: R16's
// v[32] spilled whr to scratch -> 39GB HBM refetch, 29ms).
// 256 WGs x 512 thr (1/CU). WG = (dir, batch-group of 8, 16-cell slice).
// 8 independent (dir,bg) pipelines of 32 WGs.

#define Bv 32
#define Tv 512
#define Dv 512
#define Hv 512
#define XS 520            // x LDS row stride (floats)
#define HS 520            // h LDS row stride
#define PUN 16896         // dword union: max(8*HS=4160, 512*33=16896)

__device__ __forceinline__ float sigmf_(float x) { return 1.0f / (1.0f + __expf(-x)); }
__device__ __forceinline__ float tanhf_(float x) { return 2.0f / (1.0f + __expf(-2.0f * x)) - 1.0f; }

__global__ __launch_bounds__(512, 2) void bilstm_coop7(
    const float* __restrict__ x, const int* __restrict__ lengths,
    const float* __restrict__ Wih_f, const float* __restrict__ Whh_f,
    const float* __restrict__ bih_f, const float* __restrict__ bhh_f,
    const float* __restrict__ Wih_b, const float* __restrict__ Whh_b,
    const float* __restrict__ bih_b, const float* __restrict__ bhh_b,
    float* __restrict__ out, unsigned int* __restrict__ cnt)  // cnt: 8 groups x 64 uints
{
    __shared__ float xb[2][8 * XS];    // double-buffered x stage (33 KB)
    __shared__ float hu[PUN];          // h stage / partial union (67.6 KB)
    __shared__ float gates[64 * 9];    // [row 64][b 8] pad 9
    __shared__ float bias_s[64];

    const int tid  = threadIdx.x;
    const int w    = blockIdx.x;

    // blockIdx -> XCD is (w & 7). XCDs 0..3 = dir 0, XCDs 4..7 = dir 1.
    // cslice is XCD-local (8 per XCD) -> per-XCD Wih slice = 1MB, L2-resident.
    const int xcd    = w & 7;
    const int slot   = w >> 3;                      // 0..31
    const int dir    = xcd >> 2;
    const int cslice = (xcd & 3) * 8 + (slot & 7);  // 0..31
    const int bg     = slot >> 3;                   // 0..3
    const int c0     = cslice * 16;                 // first of 16 cells
    const int b0     = bg * 8;                      // first of 8 batches
    const int group  = dir * 4 + bg;                // 0..7

    unsigned int* slotA = cnt + (size_t)group * 64 + cslice;        // wave-6 flag
    unsigned int* slotB = cnt + (size_t)group * 64 + 32 + cslice;   // wave-7 flag

    const float* Wih = dir ? Wih_b : Wih_f;
    const float* Whh = dir ? Whh_b : Whh_f;
    const float* bih = dir ? bih_b : bih_f;
    const float* bhh = dir ? bhh_b : bhh_f;

    // ---- prologue ----
    if (tid == 0) {
        __hip_atomic_store(slotA, 0u, __ATOMIC_RELAXED, __HIP_MEMORY_SCOPE_AGENT);
        __hip_atomic_store(slotB, 0u, __ATOMIC_RELAXED, __HIP_MEMORY_SCOPE_AGENT);
    }
    if (tid < 64) {
        int g = tid >> 4, cell = tid & 15;
        int rg = g * Hv + c0 + cell;
        bias_s[tid] = bih[rg] + bhh[rg];
    }
    // stage x(0) into xb[0]
    {
        const int t0 = dir ? (Tv - 1) : 0;
        #pragma unroll
        for (int j = 0; j < 2; ++j) {
            int F  = tid + j * 512;
            int bl = F >> 7, cf = F & 127;
            *(float4*)(&xb[0][bl * XS + cf * 4]) =
                *(const float4*)(x + ((size_t)(b0 + bl) * Tv + t0) * Dv + cf * 4);
        }
    }
    cg::this_grid().sync();   // once per launch: slots zeroed + xb[0] ready

    // thread tile: pos = 4 gate-rows, all 8 batches, 32-float k-segment
    const int pos  = tid >> 5;      // 0..15 -> rows pos*4 .. pos*4+3 (of 64)
    const int kseg = tid & 31;      // 0..31

    int wrow[4];
    #pragma unroll
    for (int i = 0; i < 4; ++i) {
        int r = pos * 4 + i;
        wrow[i] = (r >> 4) * Hv + c0 + (r & 15);
    }

    // step-invariant Whh slice in registers (16 x float4, as in R15)
    float4 whr[4][4];
    #pragma unroll
    for (int j = 0; j < 4; ++j)
        #pragma unroll
        for (int i = 0; i < 4; ++i)
            whr[j][i] = *(const float4*)(Whh + (size_t)wrow[i] * Dv
                                             + (j * 32 + kseg) * 4);

    // tail threads (waves 6,7): idx 0..127 -> (batch, cell)
    const int tidx    = tid - 384;          // valid when tid >= 384
    const int pw_ib   = tidx >> 4;          // 0..7
    const int pw_cell = tidx & 15;          // 0..15
    float cst_r = 0.0f;
    int   len_r = 0;
    if (tid >= 384) len_r = lengths[b0 + pw_ib];

    for (int s = 0; s < Tv; ++s) {
        const int t   = dir ? (Tv - 1 - s) : s;
        const int cur = s & 1;

        // ---- 1. x-part GEMM from xb[cur] (prefetched last step) ----
        float acc[4][8];
        #pragma unroll
        for (int i = 0; i < 4; ++i)
            #pragma unroll
            for (int ib = 0; ib < 8; ++ib) acc[i][ib] = 0.0f;

        #pragma unroll
        for (int j = 0; j < 4; ++j) {
            const int col = (j * 32 + kseg) * 4;
            float4 wv[4];
            #pragma unroll
            for (int i = 0; i < 4; ++i)
                wv[i] = *(const float4*)(Wih + (size_t)wrow[i] * Dv + col);
            float4 xv[8];
            #pragma unroll
            for (int ib = 0; ib < 8; ++ib)
                xv[ib] = *(const float4*)(&xb[cur][ib * XS + col]);
            #pragma unroll
            for (int i = 0; i < 4; ++i)
                #pragma unroll
                for (int ib = 0; ib < 8; ++ib)
                    acc[i][ib] += wv[i].x * xv[ib].x + wv[i].y * xv[ib].y
                                + wv[i].z * xv[ib].z + wv[i].w * xv[ib].w;
        }

        // ---- 2. prefetch x(s+1) into xb[cur^1] (off critical path) ----
        if (s + 1 < Tv) {
            const int tn = dir ? (Tv - 2 - s) : (s + 1);
            #pragma unroll
            for (int j = 0; j < 2; ++j) {
                int F  = tid + j * 512;
                int bl = F >> 7, cf = F & 127;
                *(float4*)(&xb[cur ^ 1][bl * XS + cf * 4]) =
                    *(const float4*)(x + ((size_t)(b0 + bl) * Tv + tn) * Dv + cf * 4);
            }
        }

        // ---- 3. WAIT: tid<64 poll 64 packed slots (4 lines/round) ----
        if (s > 0 && tid < 64) {
            const unsigned int tgt = (unsigned int)s;
            const unsigned int* sl = cnt + (size_t)group * 64 + tid;
            while (__hip_atomic_load(sl, __ATOMIC_RELAXED,
                                     __HIP_MEMORY_SCOPE_AGENT) < tgt)
                __builtin_amdgcn_s_sleep(1);
        }
        __syncthreads();   // [B] barrier passed; xb[cur^1] complete; tail rejoined

        // ---- 4. stage h_{s-1} from out (fresh addresses -> L2 miss -> LLC) ----
        if (s == 0) {
            #pragma unroll
            for (int j = 0; j < 2; ++j) {
                int F  = tid + j * 512;
                int bl = F >> 7, cf = F & 127;
                *(float4*)(hu + bl * HS + cf * 4) = make_float4(0.f, 0.f, 0.f, 0.f);
            }
        } else {
            const int tp = dir ? (t + 1) : (t - 1);
            #pragma unroll
            for (int j = 0; j < 2; ++j) {
                int F  = tid + j * 512;
                int bl = F >> 7, cf = F & 127;
                *(float4*)(hu + bl * HS + cf * 4) =
                    *(const float4*)(out + ((size_t)(b0 + bl) * Tv + tp) * (2 * Hv)
                                         + dir * Hv + cf * 4);
            }
        }
        __syncthreads();   // [C] hu ready

        // hold-value for masked batches (tail waves, before hu is aliased)
        float hpv = 0.0f;
        if (tid >= 384) hpv = hu[pw_ib * HS + c0 + pw_cell];

        // ---- 5. h-part GEMM: pure LDS + register weights ----
        #pragma unroll
        for (int j = 0; j < 4; ++j) {
            const int col = (j * 32 + kseg) * 4;
            float4 hv[8];
            #pragma unroll
            for (int ib = 0; ib < 8; ++ib)
                hv[ib] = *(const float4*)(hu + ib * HS + col);
            #pragma unroll
            for (int i = 0; i < 4; ++i)
                #pragma unroll
                for (int ib = 0; ib < 8; ++ib)
                    acc[i][ib] += whr[j][i].x * hv[ib].x + whr[j][i].y * hv[ib].y
                                + whr[j][i].z * hv[ib].z + whr[j][i].w * hv[ib].w;
        }
        __syncthreads();   // [D] hu reads + hpv done; alias as partial[512][33]

        // ---- 6. partial dump: part[(row*8+ib)][kseg], pad 33 ----
        float* part = hu;
        #pragma unroll
        for (int i = 0; i < 4; ++i) {
            const int r = pos * 4 + i;
            #pragma unroll
            for (int ib = 0; ib < 8; ++ib)
                part[(r * 8 + ib) * 33 + kseg] = acc[i][ib];
        }
        __syncthreads();   // [E]

        // ---- 7. final reduce + bias -> gates[row][ib] ----
        {
            const float* pr = part + tid * 33;   // row*8+ib == tid
            float s0 = 0.f, s1 = 0.f, s2 = 0.f, s3 = 0.f;
            #pragma unroll
            for (int m = 0; m < 32; m += 4) {
                s0 += pr[m + 0]; s1 += pr[m + 1]; s2 += pr[m + 2]; s3 += pr[m + 3];
            }
            gates[(tid >> 3) * 9 + (tid & 7)] =
                ((s0 + s1) + (s2 + s3)) + bias_s[tid >> 3];
        }
        __syncthreads();   // [F] gates ready; waves 0..5 sprint to next x-GEMM

        // ---- 8. TAIL (waves 6,7): pointwise, coalesced sc1 publish ----
        if (tid >= 384) {
            float gi = sigmf_(gates[( 0 + pw_cell) * 9 + pw_ib]);
            float gf = sigmf_(gates[(16 + pw_cell) * 9 + pw_ib]);
            float gg = tanhf_(gates[(32 + pw_cell) * 9 + pw_ib]);
            float go = sigmf_(gates[(48 + pw_cell) * 9 + pw_ib]);
            float cn = gf * cst_r + gi * gg;
            float hn = go * tanhf_(cn);
            const bool vld = (t < len_r);
            float ho = vld ? hn : hpv;
            cst_r = vld ? cn : cst_r;
            // consecutive tid -> consecutive cell -> 64B-line coalesced
            __hip_atomic_store(out + ((size_t)(b0 + pw_ib) * Tv + t) * (2 * Hv)
                                   + dir * Hv + c0 + pw_cell,
                               ho, __ATOMIC_RELAXED, __HIP_MEMORY_SCOPE_AGENT);
        }
        // ---- 9. per-wave RELEASE (vmcnt drains only that wave's stores) ----
        if (tid == 384)
            __hip_atomic_store(slotA, (unsigned int)(s + 1),
                               __ATOMIC_RELEASE, __HIP_MEMORY_SCOPE_AGENT);
        if (tid == 448)
            __hip_atomic_store(slotB, (unsigned int)(s + 1),
                               __ATOMIC_RELEASE, __HIP_MEMORY_SCOPE_AGENT);
        // no trailing sync: next step's [B] rejoins; hu not overwritten until
        // after next [B], so tail's gates/hpv reads are safe.
    }
}

// ---------------- fallback: R10 kernel (unchanged, correct, slow) ----------------
__global__ __launch_bounds__(1024, 1) void bilstm_simple(
    const float* __restrict__ x,
    const int* __restrict__ lengths,
    const float* __restrict__ Wih_f, const float* __restrict__ Whh_f,
    const float* __restrict__ bih_f, const float* __restrict__ bhh_f,
    const float* __restrict__ Wih_b, const float* __restrict__ Whh_b,
    const float* __restrict__ bih_b, const float* __restrict__ bhh_b,
    float* __restrict__ out)
{
    __shared__ float xh[Dv + Hv];
    __shared__ float cst[Hv];
    __shared__ float gates[4 * Hv];
    __shared__ float bias[4 * Hv];

    const int tid  = threadIdx.x;
    const int wave = tid >> 6;
    const int lane = tid & 63;
    const int dir  = blockIdx.x >> 5;
    const int b    = blockIdx.x & 31;

    const float* Wih = dir ? Wih_b : Wih_f;
    const float* Whh = dir ? Whh_b : Whh_f;
    const float* bih = dir ? bih_b : bih_f;
    const float* bhh = dir ? bhh_b : bhh_f;

    for (int i = tid; i < 4 * Hv; i += 1024) bias[i] = bih[i] + bhh[i];
    for (int i = tid; i < Hv; i += 1024) { xh[Dv + i] = 0.f; cst[i] = 0.f; }
    const int len = lengths[b];

    const float* Wbase = (lane < 32) ? Wih : Whh;
    const int koff = (lane & 31) * 16;

    for (int s = 0; s < Tv; ++s) {
        const int t = dir ? (Tv - 1 - s) : s;
        __syncthreads();
        for (int i = tid; i < Dv; i += 1024)
            xh[i] = x[((size_t)b * Tv + t) * Dv + i];
        __syncthreads();

        float4 xr0 = *(const float4*)(xh + lane * 16 + 0);
        float4 xr1 = *(const float4*)(xh + lane * 16 + 4);
        float4 xr2 = *(const float4*)(xh + lane * 16 + 8);
        float4 xr3 = *(const float4*)(xh + lane * 16 + 12);

        #pragma unroll 4
        for (int rr = 0; rr < 128; ++rr) {
            const int row = wave * 128 + rr;
            const float4* wr = (const float4*)(Wbase + (size_t)row * 512 + koff);
            const float4 w0 = wr[0], w1 = wr[1], w2 = wr[2], w3 = wr[3];
            float acc = w0.x * xr0.x + w0.y * xr0.y + w0.z * xr0.z + w0.w * xr0.w
                      + w1.x * xr1.x + w1.y * xr1.y + w1.z * xr1.z + w1.w * xr1.w
                      + w2.x * xr2.x + w2.y * xr2.y + w2.z * xr2.z + w2.w * xr2.w
                      + w3.x * xr3.x + w3.y * xr3.y + w3.z * xr3.z + w3.w * xr3.w;
            #pragma unroll
            for (int off = 32; off > 0; off >>= 1)
                acc += __shfl_xor(acc, off, 64);
            if (lane == 0) gates[row] = acc;
        }
        __syncthreads();

        if (tid < Hv) {
            const int cc = tid;
            const float gi = sigmf_(gates[0 * Hv + cc] + bias[0 * Hv + cc]);
            const float gf = sigmf_(gates[1 * Hv + cc] + bias[1 * Hv + cc]);
            const float gg = tanhf_(gates[2 * Hv + cc] + bias[2 * Hv + cc]);
            const float go = sigmf_(gates[3 * Hv + cc] + bias[3 * Hv + cc]);
            const float cn = gf * cst[cc] + gi * gg;
            const float hn = go * tanhf_(cn);
            const bool v = (t < len);
            const float hnew = v ? hn : xh[Dv + cc];
            cst[cc] = v ? cn : cst[cc];
            xh[Dv + cc] = hnew;
            out[((size_t)b * Tv + t) * (2 * Hv) + dir * Hv + cc] = hnew;
        }
    }
}

extern "C" void kernel_launch(void* const* d_in, const int* in_sizes, int n_in,
                              void* d_out, int out_size, void* d_ws, size_t ws_size,
                              hipStream_t stream) {
    (void)out_size;

    const void *xv, *len_p, *Wihf, *Whhf, *bihf, *bhhf, *Wihb, *Whhb, *bihb, *bhhb;
    if (n_in == 10 && in_sizes[9] == 8388608 && in_sizes[8] == 32) {
        // alphabetical pytree order fallback
        Whhb = d_in[0]; Whhf = d_in[1]; Wihb = d_in[2]; Wihf = d_in[3];
        bhhb = d_in[4]; bhhf = d_in[5]; bihb = d_in[6]; bihf = d_in[7];
        len_p = d_in[8]; xv = d_in[9];
    } else {
        // documented dict order
        xv = d_in[0]; len_p = d_in[1];
        Wihf = d_in[2]; Whhf = d_in[3]; bihf = d_in[4]; bhhf = d_in[5];
        Wihb = d_in[6]; Whhb = d_in[7]; bihb = d_in[8]; bhhb = d_in[9];
    }

    const float* xf  = (const float*)xv;
    const int*   lp  = (const int*)len_p;
    const float* wif = (const float*)Wihf;  const float* whf = (const float*)Whhf;
    const float* bif = (const float*)bihf;  const float* bhf = (const float*)bhhf;
    const float* wib = (const float*)Wihb;  const float* whb = (const float*)Whhb;
    const float* bib = (const float*)bihb;  const float* bhb = (const float*)bhhb;
    float* outp = (float*)d_out;
    unsigned int* cntp = (unsigned int*)d_ws;

    if (ws_size >= 8 * 64 * sizeof(unsigned int)) {   // 2 KB of slots
        void* args[12] = { &xf, &lp, &wif, &whf, &bif, &bhf,
                           &wib, &whb, &bib, &bhb, &outp, &cntp };
        hipError_t e = hipLaunchCooperativeKernel((const void*)bilstm_coop7,
                                                  dim3(256), dim3(512),
                                                  args, 0, stream);
        if (e == hipSuccess) return;
    }

    // fallback: R10 kernel
    bilstm_simple<<<dim3(64), dim3(1024), 0, stream>>>(
        xf, lp, wif, whf, bif, bhf, wib, whb, bib, bhb, outp);
}